// Round 11
// baseline (138.467 us; speedup 1.0000x reference)
//
#include <hip/hip_runtime.h>

// pred_vol (1,1,64,512,512) fp32; thresh 0.5; 9x9x9 max-pool NMS.
// Identity: thr is monotone and the window contains the center, so
// reference output == (c > 0.5 && c == max999_raw(x)) ? c : 0.
//
// v11 = v5's occupancy/rings (TH=4, 512 thr, 2 blocks/CU) with W-max moved
// to STAGING TIME (register staging, not DMA):
//  - stager: 3 segments/wave, each = 3 global loads (mid, +-16B) ->
//    9-wide W-window in regs -> ONE ds_write_b128 of the W-maxed row.
//  - consumer: 9 ds_reads of Wmax rows -> vertical tree -> pm DIRECTLY.
//    No bcol pass, no horizontal LDS reads, ONE barrier per step.
//  - segment map: wave w=(q<<1|h) stages rows {q,4+q,8+q} at half h; its
//    k=1 mid float4 IS its own output row's raw center -> C-ring (depth 6)
//    costs zero extra loads. (Mapping verified: consumer wave = 2*hr+half.)
//  - dbuf wm (48 KB): loads(p)@step p-2, ds_write(p)@step p-1, reads@p;
//    in-flight a full step (~2000cy > HBM 900cy). Counted vmcnt barriers.
// LDS wave-ops/CU-step 240 -> 192 and the bcol write->barrier->read chain
// is gone; VALU takes the W-max work (headroom: 30% busy in v5).
static constexpr int Dd = 64;
static constexpr int Hh = 512;
static constexpr int Ww = 512;
static constexpr int RAD = 4;
static constexpr float THRESH_V = 0.5f;
static constexpr int W4 = Ww / 4;           // 128 float4 per row
static constexpr int PLANE4 = Hh * W4;      // 65536 float4 per D-plane

static constexpr int TH = 4;                // output h-rows per block
static constexpr int DC = 16;               // output d-planes per block
static constexpr int ROWS = TH + 2 * RAD;   // 12 Wmax rows per plane
static constexpr int NPL = DC + 2 * RAD;    // 24 planes; 24 steps
static constexpr int NBLK = (Hh / TH) * (Dd / DC);  // 512 blocks (2/CU)

typedef float nf4 __attribute__((ext_vector_type(4)));

__device__ __forceinline__ float4 f4max(float4 a, float4 b) {
    return make_float4(fmaxf(a.x, b.x), fmaxf(a.y, b.y), fmaxf(a.z, b.z), fmaxf(a.w, b.w));
}
__device__ __forceinline__ int iclamp(int v, int lo, int hi) {
    return v < lo ? lo : (v > hi ? hi : v);
}

// Single barrier per step: publishes last step's wm writes (lgkmcnt(0)) and
// drains this step's staging loads (counted vmcnt leaves the store in flight).
#define BAR_VM(N) asm volatile("s_waitcnt vmcnt(" #N ") lgkmcnt(0)\n\ts_barrier" ::: "memory")

// (512,2): 2 blocks/CU (16 waves), 128-VGPR cap. LDS 48 KB -> fits easily.
__global__ __launch_bounds__(512, 2)
void fused_nms_k11(const float4* __restrict__ x4, float4* __restrict__ o4) {
    // double-buffered W-maxed rows: 2 * 12 * 128 * 16 B = 48 KB. No bcol.
    __shared__ float4 wm[2][ROWS * W4];

    const int tid  = threadIdx.x;
    const int w4   = tid & (W4 - 1);   // 0..127 (consumer column)
    const int hr   = tid >> 7;         // 0..3   (consumer output row)
    const int wid  = tid >> 6;         // wave 0..7
    const int lane = tid & 63;
    const int q    = wid >> 1;         // staging row-group 0..3
    const int hh   = wid & 1;          // staging half-row 0/1

    // XCD swizzle: band = blockIdx&7 -> h-band of 64 rows stays on one XCD's L2
    const int b    = blockIdx.x;
    const int band = b & 7;
    const int rest = b >> 3;           // 0..63
    const int ht   = band * 16 + (rest & 15);  // 0..127
    const int dc   = rest >> 4;        // 0..3
    const int h0   = ht * TH;
    const int d0   = dc * DC;
    const int outrow = (h0 + hr) * W4 + w4;

    // Staging descriptors: wave w stages rows {q, 4+q, 8+q} at half hh.
    // Bijection over 12 rows x 2 halves. Per segment: mid + left/right
    // (+-1 float4, W-clamped) global offsets, and the LDS element offset.
    int gl[3], gm[3], gr[3], lw[3];
    const int rowk0 = q, rowk1 = 4 + q, rowk2 = 8 + q;
    const int rks[3] = {rowk0, rowk1, rowk2};
#pragma unroll
    for (int k = 0; k < 3; ++k) {
        const int gh = iclamp(h0 - RAD + rks[k], 0, Hh - 1);
        const int c  = hh * 64 + lane;            // the w4 this lane stages
        gm[k] = gh * W4 + c;
        gl[k] = gh * W4 + (c ? c - 1 : 0);
        gr[k] = gh * W4 + (c < W4 - 1 ? c + 1 : W4 - 1);
        lw[k] = rks[k] * W4 + c;
    }

    // In-flight staging registers (one plane's worth, ~36 VGPR).
    float4 La[3], Lm[3], Lr[3];
    auto issue = [&](int p) {   // issue 9 global loads for plane index p
        const float4* pl = x4 + (size_t)iclamp(d0 - RAD + p, 0, Dd - 1) * PLANE4;
#pragma unroll
        for (int k = 0; k < 3; ++k) {
            La[k] = pl[gl[k]];
            Lm[k] = pl[gm[k]];
            Lr[k] = pl[gr[k]];
        }
    };
    // 9-wide W-window max from 3 raw float4s (clamped edges match v5 hwin).
    auto wmax4 = [&](float4 lm, float4 cm, float4 rm) -> float4 {
        const float l3 = lm.w, l2 = fmaxf(lm.z, l3), l1 = fmaxf(lm.y, l2), l0 = fmaxf(lm.x, l1);
        const float core = fmaxf(fmaxf(cm.x, cm.y), fmaxf(cm.z, cm.w));
        const float r0 = rm.x, r1 = fmaxf(r0, rm.y), r2 = fmaxf(r1, rm.z), r3 = fmaxf(r2, rm.w);
        float4 o;
        o.x = fmaxf(l0, fmaxf(core, r0));
        o.y = fmaxf(l1, fmaxf(core, r1));
        o.z = fmaxf(l2, fmaxf(core, r2));
        o.w = fmaxf(l3, fmaxf(core, r3));
        return o;
    };

    // R: 8-slot ring of pm (full HxW max rows). D-window at step t =
    // max(R[0..7], pm(t)) -> output plane d0 + t - 8, center plane t-4.
    // C: depth-6 ring of raw centers. Lm[1] (row 4+q, half hh) at plane p
    // == raw[p][4+hr][w4] for THIS thread (consumer wave = 2*hr+half == wid).
    // Written at step p-1 (slot p%6), read at step p+4 (slot (t-4)%6). Slots
    // never collide (5 != 0 mod 6).
    float4 R[8], C[6];

    // Prologue: plane 0 loaded+Wmax'd+written; plane 1 loads in flight.
    issue(0);
    {
#pragma unroll
        for (int k = 0; k < 3; ++k) wm[0][lw[k]] = wmax4(La[k], Lm[k], Lr[k]);
        C[0] = Lm[1];
    }
    issue(1);

    // 24 steps, fully unrolled: parities/slots/vmcnt counts all static.
#pragma unroll
    for (int t = 0; t < NPL; ++t) {
        const bool doE = (t >= 8);   // emit output plane d0 + t - 8

        // Barrier: publishes wm writes(t) from step t-1 (lgkmcnt 0) and
        // drains loads(t+1) issued at step t-1. Outstanding after those
        // loads: store(t-1) [t>=9] -> N=1, else 0.
        if (t <= 8) { BAR_VM(0); } else { BAR_VM(1); }

        // Stage-write plane t+1 (Wmax in regs -> LDS), capture its center.
        if (t + 1 < NPL) {
            float4* dst = wm[(t + 1) & 1];
#pragma unroll
            for (int k = 0; k < 3; ++k) dst[lw[k]] = wmax4(La[k], Lm[k], Lr[k]);
            C[(t + 1) % 6] = Lm[1];
        }
        __builtin_amdgcn_sched_barrier(0);
        // Issue loads for plane t+2 (in flight ~1 full step).
        if (t + 2 < NPL) issue(t + 2);
        __builtin_amdgcn_sched_barrier(0);

        // Vertical 9-window on Wmax rows hr..hr+8 -> pm directly.
        const float4* Bc = &wm[t & 1][tid];   // tid == hr*W4 + w4
        float4 r0 = Bc[0 * W4], r1 = Bc[1 * W4], r2 = Bc[2 * W4], r3 = Bc[3 * W4];
        float4 r4 = Bc[4 * W4], r5 = Bc[5 * W4], r6 = Bc[6 * W4], r7 = Bc[7 * W4];
        float4 r8 = Bc[8 * W4];
        float4 pm = f4max(f4max(f4max(r0, r1), f4max(r2, r3)),
                          f4max(f4max(r4, r5), f4max(f4max(r6, r7), r8)));

        if (doE) {
            const float4 cen = C[(t - 4) % 6];   // raw center, plane t-4
            float4 mm = pm;
#pragma unroll
            for (int i = 0; i < 8; ++i) mm = f4max(mm, R[i]);
            nf4 qv;
            qv.x = (cen.x > THRESH_V && cen.x == mm.x) ? cen.x : 0.0f;
            qv.y = (cen.y > THRESH_V && cen.y == mm.y) ? cen.y : 0.0f;
            qv.z = (cen.z > THRESH_V && cen.z == mm.z) ? cen.z : 0.0f;
            qv.w = (cen.w > THRESH_V && cen.w == mm.w) ? cen.w : 0.0f;
            __builtin_nontemporal_store(
                qv, (nf4*)&o4[(size_t)(d0 + t - 8) * PLANE4 + outrow]);
        }
        R[t & 7] = pm;   // overwrite after use
    }
}

extern "C" void kernel_launch(void* const* d_in, const int* in_sizes, int n_in,
                              void* d_out, int out_size, void* d_ws, size_t ws_size,
                              hipStream_t stream) {
    const float4* x4 = (const float4*)d_in[0];
    float4* out4 = (float4*)d_out;
    (void)d_ws; (void)ws_size; (void)in_sizes; (void)n_in; (void)out_size;
    fused_nms_k11<<<dim3(NBLK), dim3(512), 0, stream>>>(x4, out4);
}

// Round 13
// 119.118 us; speedup vs baseline: 1.1624x; 1.1624x over previous
//
#include <hip/hip_runtime.h>

// pred_vol (1,1,64,512,512) fp32; thresh 0.5; 9x9x9 max-pool NMS.
// Identity: thr is monotone and the window contains the center, so
// reference output == (c > 0.5 && c == max999_raw(x)) ? c : 0.
//
// v13 = v12 with the C-ring bug fixed (depth-4, v5-exact). v12's failure:
// C[t%5] read at emit delivers the center captured at step t-5, but in
// this two-barrier structure the emitted plane d0+t-8 has plane index t-4
// -> need C written at step t-4 -> depth-4 ring C[t&3] (v5's original).
// The depth-5 ring belongs ONLY to the single-barrier pipelines (emit
// plane index t-5). Q paired partials verified correct (every Q[i] read
// at emit t covers only pm values in [t-8, t-1]).
//
// Structure (v5 champion, measured ~40us): TH=4/DC=16, 512 thr, 2 blocks/CU;
// global_load_lds staging of 12 raw rows (24 segs, 3/wave); triple-buffered
// braw, distance-2 prefetch, counted-vmcnt barriers; per-thread vertical
// 9-max; bcol + prefix/suffix horizontal; C-ring centers; 8-slot D-ring
// with paired partials Q (emit fold 8 -> 5 f4max).
//
// Failed-lever ledger (do not revisit): DPP wave_shr/shl (illegal on CDNA,
// -25%), TH=8 sharing (VGPR rings spill past 128 cap), 1024-thr (compiler
// VGPR-64 throttle + bank conflicts), 1-block/CU tiles (latency-bound,
// flat), register staging (L1 thrash, 2.5x), barrier merge at 1/CU (flat).
static constexpr int Dd = 64;
static constexpr int Hh = 512;
static constexpr int Ww = 512;
static constexpr int RAD = 4;
static constexpr float THRESH_V = 0.5f;
static constexpr int W4 = Ww / 4;           // 128 float4 per row
static constexpr int PLANE4 = Hh * W4;      // 65536 float4 per D-plane

static constexpr int TH = 4;                // output h-rows per block
static constexpr int DC = 16;               // output d-planes per block
static constexpr int ROWS = TH + 2 * RAD;   // 12 staged raw rows per plane
static constexpr int NPL = DC + 2 * RAD;    // 24 d-steps per block
static constexpr int NBLK = (Hh / TH) * (Dd / DC);  // 512 blocks (2/CU)

typedef float nf4 __attribute__((ext_vector_type(4)));

__device__ __forceinline__ float4 f4max(float4 a, float4 b) {
    return make_float4(fmaxf(a.x, b.x), fmaxf(a.y, b.y), fmaxf(a.z, b.z), fmaxf(a.w, b.w));
}
__device__ __forceinline__ int iclamp(int v, int lo, int hi) {
    return v < lo ? lo : (v > hi ? hi : v);
}

// Counted-vmcnt barrier: drains this wave's stage(t) DMA group while newer
// prefetch groups and output stores stay in flight. lgkmcnt(0) orders LDS.
#define BAR_VM(N) asm volatile("s_waitcnt vmcnt(" #N ") lgkmcnt(0)\n\ts_barrier" ::: "memory")
// LDS-only barrier: publishes bcol writes without touching VMEM counters.
#define BAR_LDS() asm volatile("s_waitcnt lgkmcnt(0)\n\ts_barrier" ::: "memory")

// Direct global->LDS DMA, 16B per lane, dest = wave-uniform base + lane*16.
__device__ __forceinline__ void load_lds16(const float4* g, float4* l) {
    __builtin_amdgcn_global_load_lds(
        (const __attribute__((address_space(1))) void*)g,
        (__attribute__((address_space(3))) void*)l, 16, 0, 0);
}

// (512,2): 2 blocks/CU, 128-VGPR cap. 80 KB LDS = exactly 2 blocks/CU.
__global__ __launch_bounds__(512, 2)
void fused_nms_k13(const float4* __restrict__ x4, float4* __restrict__ o4) {
    // 3 x 12-row raw buffers (72 KB) + 4-row col-max buffer (8 KB) = 80 KB.
    __shared__ float4 braw[3][ROWS * W4];
    __shared__ float4 bcol[TH * W4];

    const int tid  = threadIdx.x;
    const int w4   = tid & (W4 - 1);   // 0..127
    const int hr   = tid >> 7;         // 0..3 (output row within block)
    const int wid  = tid >> 6;         // wave 0..7
    const int lane = tid & 63;

    // XCD swizzle: band = blockIdx&7 -> h-band of 64 rows stays on one XCD's L2
    const int b    = blockIdx.x;
    const int band = b & 7;
    const int rest = b >> 3;           // 0..63
    const int ht   = band * 16 + (rest & 15);  // 0..127
    const int dc   = rest >> 4;        // 0..3
    const int h0   = ht * TH;
    const int d0   = dc * DC;

    const int colm = w4 ? w4 - 1 : 0;
    const int colp = (w4 < W4 - 1) ? w4 + 1 : W4 - 1;
    const int outrow = (h0 + hr) * W4 + w4;

    // Staging descriptors: 24 segments (12 rows x 2 half-rows), 3 per wave.
    int goff[3], loff[3];
#pragma unroll
    for (int k = 0; k < 3; ++k) {
        const int s    = wid + 8 * k;          // 0..23
        const int row  = s >> 1;               // 0..11
        const int half = s & 1;                // 0/1
        const int gh   = iclamp(h0 - RAD + row, 0, Hh - 1);
        goff[k] = gh * W4 + half * 64 + lane;
        loff[k] = row * W4 + half * 64;
    }

    auto stage = [&](int p) {  // stage plane index p into braw[p % 3]
        const int gd = iclamp(d0 - RAD + p, 0, Dd - 1);
        const float4* pl = x4 + (size_t)gd * PLANE4;
        float4* dst = braw[p % 3];
#pragma unroll
        for (int k = 0; k < 3; ++k)
            load_lds16(pl + goff[k], dst + loff[k]);
    };

    // R: 8-slot ring of pm (planes t-8..t-1 at emit step t).
    // Q: paired partials Q[i] = max(R[2i], R[2i+1]); each Q[i] read at emit
    //    step t was refreshed within [t-8, t-1] and covers only live pms.
    // C: depth-4 center ring (v5-exact). Written at step t into C[t&3],
    //    read at emit step t from C[t&3] == written at step t-4 == plane
    //    index t-4 == the emitted plane d0+t-8. (v12 bug: depth-5 here
    //    delivered plane t-5 -> absmax 1.0.)
    float4 R[8], Q[4];
    float4 C[4];

    // Prologue: planes 0,1 staged; in-loop stage(t+2) covers 2..23.
    stage(0);
    stage(1);

    // 24 steps, fully unrolled: all parities/slots/vmcnt counts are static.
#pragma unroll
    for (int t = 0; t < NPL; ++t) {
        const bool doE = (t >= 8);   // emit output plane d0 + t - 8

        // Top barrier: guarantee stage(t) drained. Per-wave issue stream
        // after stage(t) [issued at step t-2]: store(t-2) [t>=10],
        // stage(t+1) x3 [t<=22], store(t-1) [t>=9].
        if (t <= 8)       { BAR_VM(3); }
        else if (t == 9)  { BAR_VM(4); }
        else if (t <= 22) { BAR_VM(5); }
        else              { BAR_VM(2); }

        // Distance-2 prefetch: ~2 full steps in flight.
        if (t + 2 < NPL) stage(t + 2);
        __builtin_amdgcn_sched_barrier(0);

        // Vertical 9-window max at own column (rows hr..hr+8 of the 12-row
        // span). c4 is the raw center (global row h0+hr, plane clamp(d0-4+t)
        // — exact for every emitted plane).
        const float4* Bc = &braw[t % 3][tid];   // tid == hr*W4 + w4
        float4 q0 = Bc[0 * W4], q1 = Bc[1 * W4], q2 = Bc[2 * W4], q3 = Bc[3 * W4];
        float4 c4 = Bc[4 * W4];
        float4 q5 = Bc[5 * W4], q6 = Bc[6 * W4], q7 = Bc[7 * W4], q8 = Bc[8 * W4];
        float4 m = f4max(f4max(f4max(q0, q1), f4max(q2, q3)),
                         f4max(f4max(c4, q5), f4max(f4max(q6, q7), q8)));
        bcol[tid] = m;
        BAR_LDS();

        // Horizontal 9-window via prefix/suffix from neighbor col-maxes.
        const float4 lm = bcol[hr * W4 + colm];
        const float4 rm = bcol[hr * W4 + colp];
        const float l3 = lm.w, l2 = fmaxf(lm.z, l3), l1 = fmaxf(lm.y, l2), l0 = fmaxf(lm.x, l1);
        const float core = fmaxf(fmaxf(m.x, m.y), fmaxf(m.z, m.w));
        const float r0 = rm.x, r1 = fmaxf(r0, rm.y), r2 = fmaxf(r1, rm.z), r3 = fmaxf(r2, rm.w);
        float4 pm;
        pm.x = fmaxf(l0, fmaxf(core, r0));
        pm.y = fmaxf(l1, fmaxf(core, r1));
        pm.z = fmaxf(l2, fmaxf(core, r2));
        pm.w = fmaxf(l3, fmaxf(core, r3));

        // Emit: D-window-9 = max(Q partials, current pm); center from C.
        if (doE) {
            const float4 cen = C[t & 3];   // written at step t-4 (plane t-4)
            const float4 mm = f4max(f4max(f4max(Q[0], Q[1]), f4max(Q[2], Q[3])), pm);
            nf4 q;
            q.x = (cen.x > THRESH_V && cen.x == mm.x) ? cen.x : 0.0f;
            q.y = (cen.y > THRESH_V && cen.y == mm.y) ? cen.y : 0.0f;
            q.z = (cen.z > THRESH_V && cen.z == mm.z) ? cen.z : 0.0f;
            q.w = (cen.w > THRESH_V && cen.w == mm.w) ? cen.w : 0.0f;
            __builtin_nontemporal_store(
                q, (nf4*)&o4[(size_t)(d0 + t - 8) * PLANE4 + outrow]);
        }
        // Ring + partial update (after the emit's reads). During the
        // prologue a Q entry briefly pairs with an uninitialized slot, but
        // every pair is overwritten at its odd-slot step (t=1,3,5,7) before
        // the first Q read at t=8.
        {
            const int s = t & 7;
            R[s] = pm;
            Q[s >> 1] = f4max(R[s & ~1], R[s | 1]);
        }
        C[t & 3] = c4;   // slot read above first (depth 4 == emit distance)
    }
}

extern "C" void kernel_launch(void* const* d_in, const int* in_sizes, int n_in,
                              void* d_out, int out_size, void* d_ws, size_t ws_size,
                              hipStream_t stream) {
    const float4* x4 = (const float4*)d_in[0];
    float4* out4 = (float4*)d_out;
    (void)d_ws; (void)ws_size; (void)in_sizes; (void)n_in; (void)out_size;
    fused_nms_k13<<<dim3(NBLK), dim3(512), 0, stream>>>(x4, out4);
}